// Round 2
// baseline (389.799 us; speedup 1.0000x reference)
//
#include <hip/hip_runtime.h>

// ---------------------------------------------------------------------------
// EfficientMultiHeadAttention (L=8192,B=2,E=1024,H=16,ws=256,D=64)
// cvt weights+activations to fp16 -> 3x proj GEMM (global_load_lds, BK=64,
// XOR-swizzled) -> window attention -> output GEMM (fp32 out).
// V-projection GEMM scatters directly into Vt[(b*512+c)*64+d][k] (no vtrans).
// ---------------------------------------------------------------------------

typedef _Float16 half8 __attribute__((ext_vector_type(8)));
typedef _Float16 half4 __attribute__((ext_vector_type(4)));
typedef float    f32x4 __attribute__((ext_vector_type(4)));

#define MFMA16(a, b, c) __builtin_amdgcn_mfma_f32_16x16x32_f16((a), (b), (c), 0, 0, 0)

__device__ inline void gload16(const _Float16* g, _Float16* l) {
  __builtin_amdgcn_global_load_lds(
      (const __attribute__((address_space(1))) void*)g,
      (__attribute__((address_space(3))) void*)l, 16, 0, 0);
}

// ---------------- fp32 -> fp16 convert ----------------
__global__ __launch_bounds__(256) void cvt_fp16_k(const float* __restrict__ src,
                                                  _Float16* __restrict__ dst, int n) {
  int i = (blockIdx.x * 256 + threadIdx.x) * 8;
  if (i >= n) return;
  float4 a = *(const float4*)(src + i);
  float4 b = *(const float4*)(src + i + 4);
  half8 h = {(_Float16)a.x, (_Float16)a.y, (_Float16)a.z, (_Float16)a.w,
             (_Float16)b.x, (_Float16)b.y, (_Float16)b.z, (_Float16)b.w};
  *(half8*)(dst + i) = h;
}

// ---------------- GEMM: C[m,n] = sum_k A[m,k]*W[n,k] + bias[n] ----------------
// M=16384, N=K=1024. 128x128 tile, BK=64, 4 waves (2x2), 32 mfma/wave/K-step.
// Staging: global_load_lds dwordx4, linear LDS dest, inverse-swizzled global
// source (chunk ^= row&7); ds_read_b128 with matching XOR -> 2-way (free).
// OUT_MODE: 0 = fp16 row-major (N stride), 1 = fp32 row-major, 2 = fp16
// scatter into Vt[((b*512+c)*64+d)*256 + (l&15)*16+h].
template <int OUT_MODE>
__global__ __launch_bounds__(256) void gemm_glds_k(const _Float16* __restrict__ A,
                                                   const _Float16* __restrict__ Bw,
                                                   const float* __restrict__ bias,
                                                   void* __restrict__ Cout) {
  constexpr int K = 1024, N = 1024;
  __shared__ alignas(16) _Float16 As[128 * 64];
  __shared__ alignas(16) _Float16 Bs[128 * 64];
  const int tid = threadIdx.x, lane = tid & 63, wave = tid >> 6;
  const int r15 = lane & 15, g = lane >> 4;
  const int wr = wave >> 1, wc = wave & 1;
  const int m0 = blockIdx.x * 128, n0 = blockIdx.y * 128;

  // per-lane source pattern within a 1KB (8-row) chunk: row = chunk*8 + srow,
  // k-chunk = (lane&7) ^ srow  (inverse of the read-side XOR swizzle)
  const int srow = lane >> 3;
  const int scol = ((lane & 7) ^ srow) * 8;

  f32x4 acc[4][4] = {};

  for (int k0 = 0; k0 < K; k0 += 64) {
#pragma unroll
    for (int i = 0; i < 4; i++) {
      int q = i * 4 + wave;  // A chunk q in [0,16)
      gload16(A + (size_t)(m0 + q * 8 + srow) * K + k0 + scol, &As[q * 512]);
    }
#pragma unroll
    for (int i = 0; i < 4; i++) {
      int q = i * 4 + wave;  // B chunk
      gload16(Bw + (size_t)(n0 + q * 8 + srow) * K + k0 + scol, &Bs[q * 512]);
    }
    __syncthreads();

    half8 af[4][2], bf[4][2];
#pragma unroll
    for (int mi = 0; mi < 4; mi++) {
      int row = wr * 64 + mi * 16 + r15;
#pragma unroll
      for (int kk = 0; kk < 2; kk++)
        af[mi][kk] = *(half8*)&As[row * 64 + (((kk * 4 + g) ^ (row & 7)) * 8)];
    }
#pragma unroll
    for (int ni = 0; ni < 4; ni++) {
      int row = wc * 64 + ni * 16 + r15;
#pragma unroll
      for (int kk = 0; kk < 2; kk++)
        bf[ni][kk] = *(half8*)&Bs[row * 64 + (((kk * 4 + g) ^ (row & 7)) * 8)];
    }
#pragma unroll
    for (int kk = 0; kk < 2; kk++)
#pragma unroll
      for (int mi = 0; mi < 4; mi++)
#pragma unroll
        for (int ni = 0; ni < 4; ni++)
          acc[mi][ni] = MFMA16(af[mi][kk], bf[ni][kk], acc[mi][ni]);
    __syncthreads();
  }

  // epilogue: D layout col(N) = lane&15, row(M) = (lane>>4)*4 + reg
#pragma unroll
  for (int ni = 0; ni < 4; ni++) {
    const int col = n0 + wc * 64 + ni * 16 + r15;
    const float bv = bias[col];
#pragma unroll
    for (int mi = 0; mi < 4; mi++) {
      const int rowb = m0 + wr * 64 + mi * 16 + g * 4;
#pragma unroll
      for (int r = 0; r < 4; r++) {
        float x = acc[mi][ni][r] + bv;
        if (OUT_MODE == 1) {
          ((float*)Cout)[(size_t)(rowb + r) * N + col] = x;
        } else if (OUT_MODE == 0) {
          ((_Float16*)Cout)[(size_t)(rowb + r) * N + col] = (_Float16)x;
        } else {
          // V scatter: m=(l*2+b), n=(h*64+d) -> Vt[((b*512+c)*64+d)*256 + (l&15)*16+h]
          int m = rowb + r;
          int l = m >> 1, b2 = m & 1;
          int h = col >> 6, d = col & 63;
          size_t idx = (((size_t)(b2 * 512 + (l >> 4)) * 64 + d) << 8) + ((l & 15) * 16 + h);
          ((_Float16*)Cout)[idx] = (_Float16)x;
        }
      }
    }
  }
}

// ---------------- window attention ----------------
// 8 waves x 32 q-rows. S^T = mfma(A=K rows, B=Q rows): lane owns one q-row's
// scores (k = m*16 + g*4 + reg). Softmax: in-lane reduce + shfl_xor(16,32).
// P bounced via per-wave LDS slice aliased over dead K tile; PV reads Vt (d-major).
__global__ __launch_bounds__(512) void attn_win_k(const _Float16* __restrict__ Qp,
                                                  const _Float16* __restrict__ Kp,
                                                  const _Float16* __restrict__ Vt,
                                                  _Float16* __restrict__ Y) {
  const int c = blockIdx.x, b = blockIdx.y;
  __shared__ alignas(16) _Float16 Kl[256 * 64];  // [k][d] swz chunk^=k&7; later P
  __shared__ alignas(16) _Float16 Vl[64 * 256];  // [d][k] swz chunk^=((d&7)<<2)
  const int tid = threadIdx.x, lane = tid & 63, wave = tid >> 6;
  const int i15 = lane & 15, g = lane >> 4;
  const int l0 = c * 16;

  // stage K window
#pragma unroll
  for (int i = 0; i < 4; i++) {
    int q = tid + i * 512;
    int w = q >> 3, ck = q & 7;
    int ls = l0 + (w >> 4), h = w & 15;
    half8 v = *(const half8*)(Kp + (size_t)(ls * 2 + b) * 1024 + h * 64 + ck * 8);
    *(half8*)&Kl[w * 64 + (ck ^ (w & 7)) * 8] = v;
  }
  // stage Vt window (rows contiguous)
  const size_t vb0 = (size_t)(b * 512 + c) * 64 * 256;
#pragma unroll
  for (int i = 0; i < 4; i++) {
    int q = tid + i * 512;
    int d = q >> 5, ck = q & 31;
    half8 v = *(const half8*)(Vt + vb0 + (size_t)d * 256 + ck * 8);
    *(half8*)&Vl[d * 256 + (ck ^ ((d & 7) << 2)) * 8] = v;
  }
  // Q fragments straight from global (B-operand: lane&15 = q-row)
  half8 qf[2][2];
#pragma unroll
  for (int wf = 0; wf < 2; wf++)
#pragma unroll
    for (int dh = 0; dh < 2; dh++) {
      int ls = l0 + wave * 2 + wf;
      qf[wf][dh] =
          *(const half8*)(Qp + (size_t)(ls * 2 + b) * 1024 + i15 * 64 + dh * 32 + g * 8);
    }
  __syncthreads();

  // S^T accumulate: acc[m][wf], lane holds k = m*16 + g*4 + reg for q-row
  // (wave*32 + wf*16 + i15)
  f32x4 acc[16][2] = {};
#pragma unroll
  for (int m = 0; m < 16; m++) {
    int row = m * 16 + i15;
    half8 a0 = *(half8*)&Kl[row * 64 + ((g) ^ (i15 & 7)) * 8];
    half8 a1 = *(half8*)&Kl[row * 64 + ((4 + g) ^ (i15 & 7)) * 8];
    acc[m][0] = MFMA16(a0, qf[0][0], acc[m][0]);
    acc[m][0] = MFMA16(a1, qf[0][1], acc[m][0]);
    acc[m][1] = MFMA16(a0, qf[1][0], acc[m][1]);
    acc[m][1] = MFMA16(a1, qf[1][1], acc[m][1]);
  }

  // softmax over 256 scores per q-row: scale 1/8 folded into exp arg
#pragma unroll
  for (int wf = 0; wf < 2; wf++) {
    float mx = -3.0e38f;
#pragma unroll
    for (int m = 0; m < 16; m++)
#pragma unroll
      for (int r = 0; r < 4; r++) mx = fmaxf(mx, acc[m][wf][r]);
    mx = fmaxf(mx, __shfl_xor(mx, 16, 64));
    mx = fmaxf(mx, __shfl_xor(mx, 32, 64));
    float sum = 0.f;
#pragma unroll
    for (int m = 0; m < 16; m++)
#pragma unroll
      for (int r = 0; r < 4; r++) {
        float e = __expf((acc[m][wf][r] - mx) * 0.125f);
        acc[m][wf][r] = e;
        sum += e;
      }
    sum += __shfl_xor(sum, 16, 64);
    sum += __shfl_xor(sum, 32, 64);
    float inv = 1.f / sum;
#pragma unroll
    for (int m = 0; m < 16; m++)
#pragma unroll
      for (int r = 0; r < 4; r++) acc[m][wf][r] *= inv;
  }
  __syncthreads();  // all waves done with Kl -> reuse as per-wave P buffers

  _Float16* Pw = &Kl[wave * 2048];  // [32 rows][64 k] fp16, chunk ^= row&7
  f32x4 oacc[2][4] = {};
#pragma unroll
  for (int kq = 0; kq < 4; kq++) {
    // write P slice (k in [kq*64, kq*64+64)): lane (g,i15) holds 4 consecutive k
#pragma unroll
    for (int wf = 0; wf < 2; wf++) {
      int rrow = wf * 16 + i15;
#pragma unroll
      for (int ml = 0; ml < 4; ml++) {
        f32x4 pv = acc[kq * 4 + ml][wf];
        half4 h = {(_Float16)pv[0], (_Float16)pv[1], (_Float16)pv[2], (_Float16)pv[3]};
        int ck = ml * 2 + (g >> 1);
        *(half4*)&Pw[rrow * 64 + ((ck ^ (i15 & 7)) * 8) + (g & 1) * 4] = h;
      }
    }
    asm volatile("s_waitcnt lgkmcnt(0)" ::: "memory");
    __builtin_amdgcn_sched_barrier(0);
    // PV: A = P rows (k-major), B = Vt rows (k-major)
#pragma unroll
    for (int kfl = 0; kfl < 2; kfl++) {
      half8 pa0 = *(half8*)&Pw[(i15)*64 + (((kfl * 4 + g) ^ (i15 & 7)) * 8)];
      half8 pa1 = *(half8*)&Pw[(16 + i15) * 64 + (((kfl * 4 + g) ^ (i15 & 7)) * 8)];
#pragma unroll
      for (int df = 0; df < 4; df++) {
        int drow = df * 16 + i15;
        half8 vbf =
            *(half8*)&Vl[drow * 256 + (((kq * 8 + kfl * 4 + g) ^ ((i15 & 7) << 2)) * 8)];
        oacc[0][df] = MFMA16(pa0, vbf, oacc[0][df]);
        oacc[1][df] = MFMA16(pa1, vbf, oacc[1][df]);
      }
    }
  }

  // store O to Y layout: window base ((h2*2+b)*8192 + n*256)*64, + w*64 + d
  const int h2 = c >> 5, n = c & 31;
  const size_t yb = ((size_t)(h2 * 2 + b) * 8192 + (size_t)n * 256) * 64;
#pragma unroll
  for (int wf = 0; wf < 2; wf++)
#pragma unroll
    for (int df = 0; df < 4; df++)
#pragma unroll
      for (int r = 0; r < 4; r++) {
        int w = wave * 32 + wf * 16 + g * 4 + r;
        Y[yb + (size_t)w * 64 + df * 16 + i15] = (_Float16)oacc[wf][df][r];
      }
}

// ---------------- launch ----------------
extern "C" void kernel_launch(void* const* d_in, const int* in_sizes, int n_in,
                              void* d_out, int out_size, void* d_ws, size_t ws_size,
                              hipStream_t stream) {
  const float* query = (const float*)d_in[0];
  const float* key_ = (const float*)d_in[1];
  const float* value = (const float*)d_in[2];
  const float* Wq = (const float*)d_in[3];
  const float* bq = (const float*)d_in[4];
  const float* Wk = (const float*)d_in[5];
  const float* bk = (const float*)d_in[6];
  const float* Wv = (const float*)d_in[7];
  const float* bv = (const float*)d_in[8];
  const float* Wo = (const float*)d_in[9];
  const float* bo = (const float*)d_in[10];

  _Float16* ws = (_Float16*)d_ws;
  _Float16* W16q = ws;                    // 4 x 1M halves (8 MB)
  _Float16* W16k = ws + (1 << 20);
  _Float16* W16v = ws + 2 * (1 << 20);
  _Float16* W16o = ws + 3 * (1 << 20);
  _Float16* X16 = ws + 4 * (1 << 20);     // 16M halves (32 MB), reused q/k/v, then Y
  _Float16* Vt = X16 + (1 << 24);         // 16M halves (32 MB)
  _Float16* Ybuf = X16;

  _Float16* Qp = (_Float16*)d_out;        // Q,K projections parked in d_out
  _Float16* Kp = Qp + (1 << 24);

  // weight converts
  cvt_fp16_k<<<512, 256, 0, stream>>>(Wq, W16q, 1 << 20);
  cvt_fp16_k<<<512, 256, 0, stream>>>(Wk, W16k, 1 << 20);
  cvt_fp16_k<<<512, 256, 0, stream>>>(Wv, W16v, 1 << 20);
  cvt_fp16_k<<<512, 256, 0, stream>>>(Wo, W16o, 1 << 20);

  dim3 gg(128, 8), gb(256);

  cvt_fp16_k<<<8192, 256, 0, stream>>>(query, X16, 1 << 24);
  gemm_glds_k<0><<<gg, gb, 0, stream>>>(X16, W16q, bq, (void*)Qp);

  cvt_fp16_k<<<8192, 256, 0, stream>>>(key_, X16, 1 << 24);
  gemm_glds_k<0><<<gg, gb, 0, stream>>>(X16, W16k, bk, (void*)Kp);

  cvt_fp16_k<<<8192, 256, 0, stream>>>(value, X16, 1 << 24);
  gemm_glds_k<2><<<gg, gb, 0, stream>>>(X16, W16v, bv, (void*)Vt);

  attn_win_k<<<dim3(512, 2), 512, 0, stream>>>(Qp, Kp, Vt, Ybuf);

  gemm_glds_k<1><<<gg, gb, 0, stream>>>(Ybuf, W16o, bo, d_out);

  (void)in_sizes; (void)n_in; (void)out_size; (void)ws_size;
}

// Round 3
// 333.823 us; speedup vs baseline: 1.1677x; 1.1677x over previous
//
#include <hip/hip_runtime.h>

// ---------------------------------------------------------------------------
// EfficientMultiHeadAttention (L=8192,B=2,E=1024,H=16,ws=256,D=64)
// cvt weights to fp16 -> 3x proj GEMM (A: fp32 reg-staged+cvt, B: glds,
// BK=64, XOR-swizzled) -> vtrans -> window attention -> output GEMM (f32 out).
// ---------------------------------------------------------------------------

typedef _Float16 half8 __attribute__((ext_vector_type(8)));
typedef _Float16 half4 __attribute__((ext_vector_type(4)));
typedef float    f32x4 __attribute__((ext_vector_type(4)));

#define MFMA16(a, b, c) __builtin_amdgcn_mfma_f32_16x16x32_f16((a), (b), (c), 0, 0, 0)

__device__ inline void gload16(const _Float16* g, _Float16* l) {
  __builtin_amdgcn_global_load_lds(
      (const __attribute__((address_space(1))) void*)g,
      (__attribute__((address_space(3))) void*)l, 16, 0, 0);
}

// ---------------- fp32 -> fp16 convert (weights only) ----------------
__global__ __launch_bounds__(256) void cvt_fp16_k(const float* __restrict__ src,
                                                  _Float16* __restrict__ dst, int n) {
  int i = (blockIdx.x * 256 + threadIdx.x) * 8;
  if (i >= n) return;
  float4 a = *(const float4*)(src + i);
  float4 b = *(const float4*)(src + i + 4);
  half8 h = {(_Float16)a.x, (_Float16)a.y, (_Float16)a.z, (_Float16)a.w,
             (_Float16)b.x, (_Float16)b.y, (_Float16)b.z, (_Float16)b.w};
  *(half8*)(dst + i) = h;
}

// ---------------- GEMM: C[m,n] = sum_k A[m,k]*W[n,k] + bias[n] ----------------
// M=16384, N=K=1024. 128x128 tile, BK=64, 4 waves (2x2), 32 mfma/wave/K-step.
// B staging: global_load_lds dwordx4, linear LDS dest, inverse-swizzled global
// source (chunk ^= row&7). A staging: if A_F32, reg-stage fp32 -> cvt ->
// swizzled ds_write_b128 (contiguous 1KB/wave, conflict-free); else glds.
// ds_read_b128 with matching XOR -> 2-way (free).
template <int A_F32, int OUT_F32>
__global__ __launch_bounds__(256) void gemm_glds_k(const void* __restrict__ A,
                                                   const _Float16* __restrict__ Bw,
                                                   const float* __restrict__ bias,
                                                   void* __restrict__ Cout) {
  constexpr int K = 1024, N = 1024;
  __shared__ alignas(16) _Float16 As[128 * 64];
  __shared__ alignas(16) _Float16 Bs[128 * 64];
  const int tid = threadIdx.x, lane = tid & 63, wave = tid >> 6;
  const int r15 = lane & 15, g = lane >> 4;
  const int wr = wave >> 1, wc = wave & 1;
  const int m0 = blockIdx.x * 128, n0 = blockIdx.y * 128;

  // staging geometry: chunk q covers rows q*8 .. q*8+7; lane -> srow = lane>>3,
  // source k-chunk kc = lane&7, LDS dest chunk = kc ^ srow (row&7 == srow).
  const int srow = lane >> 3, kc = lane & 7;
  const int scol = (kc ^ srow) * 8;  // pre-swizzled source col for glds path

  f32x4 acc[4][4] = {};

  for (int k0 = 0; k0 < K; k0 += 64) {
#pragma unroll
    for (int i = 0; i < 4; i++) {
      int q = i * 4 + wave;  // B chunk q in [0,16)
      gload16(Bw + (size_t)(n0 + q * 8 + srow) * K + k0 + scol, &Bs[q * 512]);
    }
    if (A_F32) {
#pragma unroll
      for (int i = 0; i < 4; i++) {
        int q = i * 4 + wave;
        const float* s = (const float*)A + (size_t)(m0 + q * 8 + srow) * K + k0 + kc * 8;
        float4 f0 = *(const float4*)s;
        float4 f1 = *(const float4*)(s + 4);
        half8 h = {(_Float16)f0.x, (_Float16)f0.y, (_Float16)f0.z, (_Float16)f0.w,
                   (_Float16)f1.x, (_Float16)f1.y, (_Float16)f1.z, (_Float16)f1.w};
        *(half8*)&As[q * 512 + srow * 64 + ((kc ^ srow) * 8)] = h;
      }
    } else {
#pragma unroll
      for (int i = 0; i < 4; i++) {
        int q = i * 4 + wave;
        gload16((const _Float16*)A + (size_t)(m0 + q * 8 + srow) * K + k0 + scol,
                &As[q * 512]);
      }
    }
    __syncthreads();

    half8 af[4][2], bf[4][2];
#pragma unroll
    for (int mi = 0; mi < 4; mi++) {
      int row = wr * 64 + mi * 16 + r15;
#pragma unroll
      for (int kk = 0; kk < 2; kk++)
        af[mi][kk] = *(half8*)&As[row * 64 + (((kk * 4 + g) ^ (row & 7)) * 8)];
    }
#pragma unroll
    for (int ni = 0; ni < 4; ni++) {
      int row = wc * 64 + ni * 16 + r15;
#pragma unroll
      for (int kk = 0; kk < 2; kk++)
        bf[ni][kk] = *(half8*)&Bs[row * 64 + (((kk * 4 + g) ^ (row & 7)) * 8)];
    }
#pragma unroll
    for (int kk = 0; kk < 2; kk++)
#pragma unroll
      for (int mi = 0; mi < 4; mi++)
#pragma unroll
        for (int ni = 0; ni < 4; ni++)
          acc[mi][ni] = MFMA16(af[mi][kk], bf[ni][kk], acc[mi][ni]);
    __syncthreads();
  }

  // epilogue: D layout col(N) = lane&15, row(M) = (lane>>4)*4 + reg
#pragma unroll
  for (int ni = 0; ni < 4; ni++) {
    const int col = n0 + wc * 64 + ni * 16 + r15;
    const float bv = bias[col];
#pragma unroll
    for (int mi = 0; mi < 4; mi++) {
      const int rowb = m0 + wr * 64 + mi * 16 + g * 4;
#pragma unroll
      for (int r = 0; r < 4; r++) {
        float x = acc[mi][ni][r] + bv;
        if (OUT_F32)
          ((float*)Cout)[(size_t)(rowb + r) * N + col] = x;
        else
          ((_Float16*)Cout)[(size_t)(rowb + r) * N + col] = (_Float16)x;
      }
    }
  }
}

// ---------------- V transpose: Vp(L,B,E) -> Vt[(b*512+c)*64 + d][256 k] ----------------
__global__ __launch_bounds__(256) void vtrans_k(const _Float16* __restrict__ Vp,
                                                _Float16* __restrict__ Vt) {
  const int c = blockIdx.x, b = blockIdx.y;
  __shared__ alignas(16) _Float16 Vl[256 * 64];  // [k][d], chunk ^= k&7
  const int tid = threadIdx.x;
  const int l0 = c * 16;
#pragma unroll
  for (int i = 0; i < 8; i++) {
    int q = tid + i * 256;
    int w = q >> 3, ck = q & 7;
    int ls = l0 + (w >> 4), h = w & 15;
    half8 v = *(const half8*)(Vp + (size_t)(ls * 2 + b) * 1024 + h * 64 + ck * 8);
    *(half8*)&Vl[w * 64 + (ck ^ (w & 7)) * 8] = v;
  }
  __syncthreads();
  const int d = tid >> 2, kcq = tid & 3;
  const size_t obase = ((size_t)(b * 512 + c) * 64 + d) * 256 + kcq * 64;
#pragma unroll
  for (int i8 = 0; i8 < 8; i8++) {
    half8 v;
#pragma unroll
    for (int j = 0; j < 8; j++) {
      int k = kcq * 64 + i8 * 8 + j;
      v[j] = Vl[k * 64 + (((d >> 3) ^ (k & 7)) * 8) + (d & 7)];
    }
    *(half8*)(Vt + obase + i8 * 8) = v;
  }
}

// ---------------- window attention ----------------
// 8 waves x 32 q-rows. S^T = mfma(A=K rows, B=Q rows): lane owns one q-row's
// scores (k = m*16 + g*4 + reg). Softmax: in-lane reduce + shfl_xor(16,32).
// P bounced via per-wave LDS slice aliased over dead K tile; PV reads Vt (d-major).
__global__ __launch_bounds__(512) void attn_win_k(const _Float16* __restrict__ Qp,
                                                  const _Float16* __restrict__ Kp,
                                                  const _Float16* __restrict__ Vt,
                                                  _Float16* __restrict__ Y) {
  const int c = blockIdx.x, b = blockIdx.y;
  __shared__ alignas(16) _Float16 Kl[256 * 64];  // [k][d] swz chunk^=k&7; later P
  __shared__ alignas(16) _Float16 Vl[64 * 256];  // [d][k] swz chunk^=((d&7)<<2)
  const int tid = threadIdx.x, lane = tid & 63, wave = tid >> 6;
  const int i15 = lane & 15, g = lane >> 4;
  const int l0 = c * 16;

  // stage K window
#pragma unroll
  for (int i = 0; i < 4; i++) {
    int q = tid + i * 512;
    int w = q >> 3, ck = q & 7;
    int ls = l0 + (w >> 4), h = w & 15;
    half8 v = *(const half8*)(Kp + (size_t)(ls * 2 + b) * 1024 + h * 64 + ck * 8);
    *(half8*)&Kl[w * 64 + (ck ^ (w & 7)) * 8] = v;
  }
  // stage Vt window (rows contiguous)
  const size_t vb0 = (size_t)(b * 512 + c) * 64 * 256;
#pragma unroll
  for (int i = 0; i < 4; i++) {
    int q = tid + i * 512;
    int d = q >> 5, ck = q & 31;
    half8 v = *(const half8*)(Vt + vb0 + (size_t)d * 256 + ck * 8);
    *(half8*)&Vl[d * 256 + (ck ^ ((d & 7) << 2)) * 8] = v;
  }
  // Q fragments straight from global (B-operand: lane&15 = q-row)
  half8 qf[2][2];
#pragma unroll
  for (int wf = 0; wf < 2; wf++)
#pragma unroll
    for (int dh = 0; dh < 2; dh++) {
      int ls = l0 + wave * 2 + wf;
      qf[wf][dh] =
          *(const half8*)(Qp + (size_t)(ls * 2 + b) * 1024 + i15 * 64 + dh * 32 + g * 8);
    }
  __syncthreads();

  // S^T accumulate: acc[m][wf], lane holds k = m*16 + g*4 + reg for q-row
  // (wave*32 + wf*16 + i15)
  f32x4 acc[16][2] = {};
#pragma unroll
  for (int m = 0; m < 16; m++) {
    int row = m * 16 + i15;
    half8 a0 = *(half8*)&Kl[row * 64 + ((g) ^ (i15 & 7)) * 8];
    half8 a1 = *(half8*)&Kl[row * 64 + ((4 + g) ^ (i15 & 7)) * 8];
    acc[m][0] = MFMA16(a0, qf[0][0], acc[m][0]);
    acc[m][0] = MFMA16(a1, qf[0][1], acc[m][0]);
    acc[m][1] = MFMA16(a0, qf[1][0], acc[m][1]);
    acc[m][1] = MFMA16(a1, qf[1][1], acc[m][1]);
  }

  // softmax over 256 scores per q-row: scale 1/8 folded into exp arg
#pragma unroll
  for (int wf = 0; wf < 2; wf++) {
    float mx = -3.0e38f;
#pragma unroll
    for (int m = 0; m < 16; m++)
#pragma unroll
      for (int r = 0; r < 4; r++) mx = fmaxf(mx, acc[m][wf][r]);
    mx = fmaxf(mx, __shfl_xor(mx, 16, 64));
    mx = fmaxf(mx, __shfl_xor(mx, 32, 64));
    float sum = 0.f;
#pragma unroll
    for (int m = 0; m < 16; m++)
#pragma unroll
      for (int r = 0; r < 4; r++) {
        float e = __expf((acc[m][wf][r] - mx) * 0.125f);
        acc[m][wf][r] = e;
        sum += e;
      }
    sum += __shfl_xor(sum, 16, 64);
    sum += __shfl_xor(sum, 32, 64);
    float inv = 1.f / sum;
#pragma unroll
    for (int m = 0; m < 16; m++)
#pragma unroll
      for (int r = 0; r < 4; r++) acc[m][wf][r] *= inv;
  }
  __syncthreads();  // all waves done with Kl -> reuse as per-wave P buffers

  _Float16* Pw = &Kl[wave * 2048];  // [32 rows][64 k] fp16, chunk ^= row&7
  f32x4 oacc[2][4] = {};
#pragma unroll
  for (int kq = 0; kq < 4; kq++) {
    // write P slice (k in [kq*64, kq*64+64)): lane (g,i15) holds 4 consecutive k
#pragma unroll
    for (int wf = 0; wf < 2; wf++) {
      int rrow = wf * 16 + i15;
#pragma unroll
      for (int ml = 0; ml < 4; ml++) {
        f32x4 pv = acc[kq * 4 + ml][wf];
        half4 h = {(_Float16)pv[0], (_Float16)pv[1], (_Float16)pv[2], (_Float16)pv[3]};
        int ck = ml * 2 + (g >> 1);
        *(half4*)&Pw[rrow * 64 + ((ck ^ (i15 & 7)) * 8) + (g & 1) * 4] = h;
      }
    }
    asm volatile("s_waitcnt lgkmcnt(0)" ::: "memory");
    __builtin_amdgcn_sched_barrier(0);
    // PV: A = P rows (k-major), B = Vt rows (k-major)
#pragma unroll
    for (int kfl = 0; kfl < 2; kfl++) {
      half8 pa0 = *(half8*)&Pw[(i15)*64 + (((kfl * 4 + g) ^ (i15 & 7)) * 8)];
      half8 pa1 = *(half8*)&Pw[(16 + i15) * 64 + (((kfl * 4 + g) ^ (i15 & 7)) * 8)];
#pragma unroll
      for (int df = 0; df < 4; df++) {
        int drow = df * 16 + i15;
        half8 vbf =
            *(half8*)&Vl[drow * 256 + (((kq * 8 + kfl * 4 + g) ^ ((i15 & 7) << 2)) * 8)];
        oacc[0][df] = MFMA16(pa0, vbf, oacc[0][df]);
        oacc[1][df] = MFMA16(pa1, vbf, oacc[1][df]);
      }
    }
  }

  // store O to Y layout: window base ((h2*2+b)*8192 + n*256)*64, + w*64 + d
  const int h2 = c >> 5, n = c & 31;
  const size_t yb = ((size_t)(h2 * 2 + b) * 8192 + (size_t)n * 256) * 64;
#pragma unroll
  for (int wf = 0; wf < 2; wf++)
#pragma unroll
    for (int df = 0; df < 4; df++)
#pragma unroll
      for (int r = 0; r < 4; r++) {
        int w = wave * 32 + wf * 16 + g * 4 + r;
        Y[yb + (size_t)w * 64 + df * 16 + i15] = (_Float16)oacc[wf][df][r];
      }
}

// ---------------- launch ----------------
extern "C" void kernel_launch(void* const* d_in, const int* in_sizes, int n_in,
                              void* d_out, int out_size, void* d_ws, size_t ws_size,
                              hipStream_t stream) {
  const float* query = (const float*)d_in[0];
  const float* key_ = (const float*)d_in[1];
  const float* value = (const float*)d_in[2];
  const float* Wq = (const float*)d_in[3];
  const float* bq = (const float*)d_in[4];
  const float* Wk = (const float*)d_in[5];
  const float* bk = (const float*)d_in[6];
  const float* Wv = (const float*)d_in[7];
  const float* bv = (const float*)d_in[8];
  const float* Wo = (const float*)d_in[9];
  const float* bo = (const float*)d_in[10];

  _Float16* ws = (_Float16*)d_ws;
  _Float16* W16q = ws;                    // 4 x 1M halves (8 MB)
  _Float16* W16k = ws + (1 << 20);
  _Float16* W16v = ws + 2 * (1 << 20);
  _Float16* W16o = ws + 3 * (1 << 20);
  _Float16* Vp = ws + 4 * (1 << 20);      // 16M halves (32 MB)
  _Float16* Vt = Vp + (1 << 24);          // 16M halves (32 MB)
  _Float16* Ybuf = Vp;                    // alias: Vp dead after vtrans

  _Float16* Qp = (_Float16*)d_out;        // Q,K projections parked in d_out
  _Float16* Kp = Qp + (1 << 24);

  cvt_fp16_k<<<512, 256, 0, stream>>>(Wq, W16q, 1 << 20);
  cvt_fp16_k<<<512, 256, 0, stream>>>(Wk, W16k, 1 << 20);
  cvt_fp16_k<<<512, 256, 0, stream>>>(Wv, W16v, 1 << 20);
  cvt_fp16_k<<<512, 256, 0, stream>>>(Wo, W16o, 1 << 20);

  dim3 gg(128, 8), gb(256);

  gemm_glds_k<1, 0><<<gg, gb, 0, stream>>>((const void*)query, W16q, bq, (void*)Qp);
  gemm_glds_k<1, 0><<<gg, gb, 0, stream>>>((const void*)key_, W16k, bk, (void*)Kp);
  gemm_glds_k<1, 0><<<gg, gb, 0, stream>>>((const void*)value, W16v, bv, (void*)Vp);

  vtrans_k<<<dim3(512, 2), 256, 0, stream>>>(Vp, Vt);
  attn_win_k<<<dim3(512, 2), 512, 0, stream>>>(Qp, Kp, Vt, Ybuf);

  gemm_glds_k<0, 1><<<gg, gb, 0, stream>>>((const void*)Ybuf, W16o, bo, d_out);

  (void)in_sizes; (void)n_in; (void)out_size; (void)ws_size;
}